// Round 12
// baseline (404.514 us; speedup 1.0000x reference)
//
#include <hip/hip_runtime.h>
#include <cstdint>

#define NN 10000
#define NE 80000
#define DIN_ 1024
#define HH 512

typedef __attribute__((ext_vector_type(8))) short bf16x8;
typedef __attribute__((ext_vector_type(4))) float f32x4;
typedef unsigned short u16;
typedef unsigned int u32;

static __device__ __forceinline__ float b2f(u16 u) {
  u32 i = ((u32)u) << 16;
  return __builtin_bit_cast(float, i);
}
static __device__ __forceinline__ u16 f2b(float f) {
  u32 i = __builtin_bit_cast(u32, f);
  u32 r = (i + 0x7fffu + ((i >> 16) & 1u)) >> 16;
  return (u16)r;
}
static __device__ __forceinline__ void unpack8(uint4 u, float* f) {
  f[0] = __builtin_bit_cast(float, u.x << 16);
  f[1] = __builtin_bit_cast(float, u.x & 0xffff0000u);
  f[2] = __builtin_bit_cast(float, u.y << 16);
  f[3] = __builtin_bit_cast(float, u.y & 0xffff0000u);
  f[4] = __builtin_bit_cast(float, u.z << 16);
  f[5] = __builtin_bit_cast(float, u.z & 0xffff0000u);
  f[6] = __builtin_bit_cast(float, u.w << 16);
  f[7] = __builtin_bit_cast(float, u.w & 0xffff0000u);
}
static __device__ __forceinline__ void load8(const u16* p, float* f) { unpack8(*(const uint4*)p, f); }

#define ASYNC_CP16(gp, lp)                                                        \
  __builtin_amdgcn_global_load_lds((__attribute__((address_space(1))) void*)(gp), \
                                   (__attribute__((address_space(3))) void*)(lp), \
                                   16, 0, 0)

// per-block dtype flags
static __device__ __forceinline__ int float_flag(const u16* xw) {
  __shared__ int c;
  if (threadIdx.x == 0) c = 0;
  __syncthreads();
  int bad = 0;
  for (int i = threadIdx.x; i < 2048; i += blockDim.x) {
    u32 e = (xw[i] >> 7) & 0xFFu;
    if (e >= 140u) bad++;  // |v|>=2^13 impossible for bf16 x~N(0,1)
  }
  if (bad) atomicAdd(&c, bad);
  __syncthreads();
  return c > 64;
}
static __device__ __forceinline__ int int64_flag(const u32* ew) {
  __shared__ int c;
  if (threadIdx.x == 0) c = 0;
  __syncthreads();
  int z = 0;
  for (int i = threadIdx.x; i < 256; i += blockDim.x)
    if (ew[2 * i + 1] == 0u) z++;
  if (z) atomicAdd(&c, z);
  __syncthreads();
  return c > 200;
}

// ---------------- edges: dtype cvt + degree count ----------------
__global__ void k_edges(const void* ei, int* esrc, int* edst, int* counts) {
  int f64 = int64_flag((const u32*)ei);
  int i = blockIdx.x * 256 + threadIdx.x;
  if (i < NE) {
    int sv, dv;
    if (f64) {
      sv = (int)((const long long*)ei)[i];
      dv = (int)((const long long*)ei)[NE + i];
    } else {
      sv = ((const int*)ei)[i];
      dv = ((const int*)ei)[NE + i];
    }
    esrc[i] = sv;
    edst[i] = dv;
    atomicAdd(&counts[dv], 1);
  } else if (i < NE + NN) {
    atomicAdd(&counts[i - NE], 1);  // self-loop
  }
}

// ---------------- work-efficient single-block scan (512 x 20) ----------------
__global__ __launch_bounds__(512) void k_scan(const int* counts, int* rowptr, int* cursor, int n) {
  __shared__ int lds[512];
  const int PER = 20;
  int t = threadIdx.x;
  int base = t * PER;
  int v[PER];
  int sum = 0;
#pragma unroll
  for (int i = 0; i < PER; i++) {
    int idx = base + i;
    v[i] = (idx < n) ? counts[idx] : 0;
    sum += v[i];
  }
  lds[t] = sum;
  __syncthreads();
  for (int off = 1; off < 512; off <<= 1) {
    int x = (t >= off) ? lds[t - off] : 0;
    __syncthreads();
    lds[t] += x;
    __syncthreads();
  }
  int run = (t > 0) ? lds[t - 1] : 0;
#pragma unroll
  for (int i = 0; i < PER; i++) {
    int idx = base + i;
    if (idx < n) {
      cursor[idx] = run;
      run += v[i];
      rowptr[idx + 1] = run;
    }
  }
  if (t == 0) rowptr[0] = 0;
}

// ---------------- fused: scatter + x convert + 20 vectors + 10 weight transposes ----------------
#define SBLK 352   // scatter blocks: ceil((NE+NN)/256)
#define XBLK 2048
struct Prep {
  const int* esrc;
  const int* edst;
  int* cursor;
  int* col;
  const void* xin;
  u16* xout;
  const void* vin[20];
  u16* vout[20];
  int vn[20];
  const void* tin[10];
  u16* tout[10];
  int tK[10], tN[10], toff[10];
};
__global__ void k_prep(Prep a) {
  __shared__ u16 tt[32][33];
  int b = blockIdx.x;
  if (b < SBLK) {
    int i = b * 256 + threadIdx.x;
    if (i < NE) {
      int p = atomicAdd(&a.cursor[a.edst[i]], 1);
      a.col[p] = a.esrc[i];
    } else if (i < NE + NN) {
      int v = i - NE;
      int p = atomicAdd(&a.cursor[v], 1);
      a.col[p] = v;  // self-loop
    }
    return;
  }
  b -= SBLK;
  int f = float_flag((const u16*)a.xin);
  if (b < XBLK) {
    const int total = NN * DIN_ / 8;
    for (int g = b * 256 + threadIdx.x; g < total; g += XBLK * 256) {
      u16 o[8];
      if (f) {
        const float* p = (const float*)a.xin + (size_t)g * 8;
#pragma unroll
        for (int i = 0; i < 8; i++) o[i] = f2b(p[i]);
      } else {
        *(uint4*)o = *((const uint4*)a.xin + g);
      }
      *((uint4*)a.xout + g) = *(const uint4*)o;
    }
  } else if (b < XBLK + 20) {
    int v = b - XBLK;
    const void* in = a.vin[v];
    u16* out = a.vout[v];
    int n = a.vn[v];
    for (int i = threadIdx.x; i < n; i += 256)
      out[i] = f ? f2b(((const float*)in)[i]) : ((const u16*)in)[i];
  } else {
    int tb = b - XBLK - 20;
    int seg = 0;
#pragma unroll
    for (int i = 1; i < 10; i++)
      if (tb >= a.toff[i]) seg = i;
    int tl = tb - a.toff[seg];
    int K = a.tK[seg], N = a.tN[seg];
    int tiles_n = N >> 5;
    int n0 = (tl % tiles_n) << 5, k0 = (tl / tiles_n) << 5;
    const void* in = a.tin[seg];
    u16* out = a.tout[seg];
    int tx = threadIdx.x & 31, ty = threadIdx.x >> 5;
    for (int r = ty; r < 32; r += 8) {
      size_t idx = (size_t)(k0 + r) * N + n0 + tx;
      tt[r][tx] = f ? f2b(((const float*)in)[idx]) : ((const u16*)in)[idx];
    }
    __syncthreads();
    for (int r = ty; r < 32; r += 8) out[(size_t)(n0 + r) * K + k0 + tx] = tt[tx][r];
  }
}

// ---------------- 128x128 MFMA GEMM, BK=32 (m97-verified), XOR-swizzled LDS, XCD mapping ----------------
__global__ __launch_bounds__(256) void k_gemm128(const u16* __restrict__ A, int lda,
                                                 const u16* __restrict__ Bt,
                                                 const u16* __restrict__ bias,
                                                 u16* __restrict__ C,
                                                 int M, int N, int K, int act,
                                                 int tiles_m, int ln_tiles_n) {
  __shared__ u16 sA[128 * 32];
  __shared__ u16 sB[128 * 32];
  int id = blockIdx.x;
  int xcd = id & 7;
  int rest = id >> 3;
  int xt = rest & ((1 << ln_tiles_n) - 1);
  int yt = ((rest >> ln_tiles_n) << 3) + xcd;
  if (yt >= tiles_m) return;
  int m0 = yt << 7, n0 = xt << 7;
  int t = threadIdx.x;
  int wave = t >> 6, lane = t & 63;

  int srow = t >> 2;
  int sk = ((t & 3) ^ ((t >> 3) & 3)) * 8;  // XOR-swizzled k-chunk
  const u16* agp[2];
  const u16* bgp[2];
  u16* la[2];
  u16* lb[2];
#pragma unroll
  for (int q = 0; q < 2; q++) {
    int row = (q << 6) + srow;
    int ra = m0 + row;
    ra = ra < M ? ra : M - 1;
    agp[q] = A + (size_t)ra * lda + sk;
    bgp[q] = Bt + (size_t)(n0 + row) * K + sk;
    int lofs = ((q << 8) + t) * 8;
    la[q] = sA + lofs;
    lb[q] = sB + lofs;
  }

  int wm = (wave >> 1) << 6, wn = (wave & 1) << 6;
  int lr = lane & 15;
  int kcs = (((lane >> 4) ^ ((lr >> 1) & 3))) * 8;

  f32x4 acc[4][4];
#pragma unroll
  for (int i = 0; i < 4; i++)
#pragma unroll
    for (int j = 0; j < 4; j++) acc[i][j] = (f32x4){0.f, 0.f, 0.f, 0.f};

  for (int k0 = 0; k0 < K; k0 += 32) {
#pragma unroll
    for (int q = 0; q < 2; q++) ASYNC_CP16(agp[q] + k0, la[q]);
#pragma unroll
    for (int q = 0; q < 2; q++) ASYNC_CP16(bgp[q] + k0, lb[q]);
    __syncthreads();
    bf16x8 a[4], b[4];
#pragma unroll
    for (int i = 0; i < 4; i++) a[i] = *(const bf16x8*)(sA + (wm + i * 16 + lr) * 32 + kcs);
#pragma unroll
    for (int j = 0; j < 4; j++) b[j] = *(const bf16x8*)(sB + (wn + j * 16 + lr) * 32 + kcs);
#pragma unroll
    for (int i = 0; i < 4; i++)
#pragma unroll
      for (int j = 0; j < 4; j++)
        acc[i][j] = __builtin_amdgcn_mfma_f32_16x16x32_bf16(a[i], b[j], acc[i][j], 0, 0, 0);
    __syncthreads();
  }

  int rbase = (lane >> 4) << 2;
#pragma unroll
  for (int j = 0; j < 4; j++) {
    int colc = n0 + wn + j * 16 + lr;
    float bv = b2f(bias[colc]);
#pragma unroll
    for (int i = 0; i < 4; i++) {
#pragma unroll
      for (int r = 0; r < 4; r++) {
        int row = m0 + wm + i * 16 + rbase + r;
        if (row < M) {
          float v = acc[i][j][r] + bv;
          if (act) v = fmaxf(v, 0.f);
          C[(size_t)row * N + colc] = f2b(v);
        }
      }
    }
  }
}

// ---------------- single-pass GATv2 attention, 2-edge ILP, 1 exp per edge (r9 best) ----------------
__global__ __launch_bounds__(256) void k_attn5(u16* __restrict__ xlr,
                                               const u16* __restrict__ att, const u16* __restrict__ bias,
                                               const int* __restrict__ rowptr, const int* __restrict__ col,
                                               int n) {
  int node = (blockIdx.x * 256 + threadIdx.x) >> 6;
  if (node >= n) return;
  int lane = threadIdx.x & 63;
  int h0 = lane * 8;
  float a[8], r[8];
  load8(att + h0, a);
  load8(xlr + (size_t)node * 1024 + 512 + h0, r);
  int e0 = rowptr[node], e1 = rowptr[node + 1];

  float m = -3e38f, s = 0.f;
  float acc[8] = {0.f, 0.f, 0.f, 0.f, 0.f, 0.f, 0.f, 0.f};
  int j0 = col[e0];
  int j1 = col[(e0 + 1 < e1) ? e0 + 1 : e0];
  uint4 raw0 = *(const uint4*)(xlr + (size_t)j0 * 1024 + h0);
  uint4 raw1 = *(const uint4*)(xlr + (size_t)j1 * 1024 + h0);

  for (int e = e0; e < e1; e += 2) {
    bool has2 = (e + 1 < e1);
    int jn0 = col[(e + 2 < e1) ? e + 2 : e1 - 1];
    int jn1 = col[(e + 3 < e1) ? e + 3 : e1 - 1];
    uint4 p0 = *(const uint4*)(xlr + (size_t)jn0 * 1024 + h0);  // prefetch next pair
    uint4 p1 = *(const uint4*)(xlr + (size_t)jn1 * 1024 + h0);
    float x0[8], x1[8];
    unpack8(raw0, x0);
    unpack8(raw1, x1);
    float pa = 0.f, pb = 0.f;
#pragma unroll
    for (int i = 0; i < 8; i++) {
      float z0 = x0[i] + r[i];
      z0 = z0 > 0.f ? z0 : 0.2f * z0;
      pa = fmaf(a[i], z0, pa);
      float z1 = x1[i] + r[i];
      z1 = z1 > 0.f ? z1 : 0.2f * z1;
      pb = fmaf(a[i], z1, pb);
    }
#pragma unroll
    for (int off = 32; off >= 1; off >>= 1) {
      pa += __shfl_xor(pa, off);
      pb += __shfl_xor(pb, off);
    }
    // edge A: exactly one exp on the critical path (new-max edge has weight 1)
    if (pa > m) {
      float al = __expf(m - pa);  // first edge: exp(-inf)=0
      s = fmaf(s, al, 1.f);
#pragma unroll
      for (int i = 0; i < 8; i++) acc[i] = fmaf(acc[i], al, x0[i]);
      m = pa;
    } else {
      float w = __expf(pa - m);
      s += w;
#pragma unroll
      for (int i = 0; i < 8; i++) acc[i] = fmaf(w, x0[i], acc[i]);
    }
    if (has2) {
      if (pb > m) {
        float al = __expf(m - pb);
        s = fmaf(s, al, 1.f);
#pragma unroll
        for (int i = 0; i < 8; i++) acc[i] = fmaf(acc[i], al, x1[i]);
        m = pb;
      } else {
        float w = __expf(pb - m);
        s += w;
#pragma unroll
        for (int i = 0; i < 8; i++) acc[i] = fmaf(w, x1[i], acc[i]);
      }
    }
    raw0 = p0;
    raw1 = p1;
  }
  float inv = 1.f / (s + 1e-16f);

  float bv[8];
  load8(bias + h0, bv);
  uint4 o;
  u32 p8[8];
#pragma unroll
  for (int i = 0; i < 8; i++) {
    float v = fmaf(acc[i], inv, bv[i]);
    v = fmaxf(v, 0.f);
    p8[i] = f2b(v);
  }
  o.x = p8[0] | (p8[1] << 16);
  o.y = p8[2] | (p8[3] << 16);
  o.z = p8[4] | (p8[5] << 16);
  o.w = p8[6] | (p8[7] << 16);
  *(uint4*)(xlr + (size_t)node * 1024 + 512 + h0) = o;  // in-place over xr half
}

// ---------------- final linear (256->2) + softmax; fp32 out ----------------
__global__ __launch_bounds__(256) void k_head(const u16* __restrict__ h2, const u16* __restrict__ lw3,
                                              const u16* __restrict__ lb3, float* __restrict__ out, int n) {
  int row = (blockIdx.x * 256 + threadIdx.x) >> 6;
  if (row >= n) return;
  int lane = threadIdx.x & 63;
  int k0 = lane * 4;
  uint2 hu = *(const uint2*)(h2 + (size_t)row * 256 + k0);
  float hx[4];
  hx[0] = __builtin_bit_cast(float, hu.x << 16);
  hx[1] = __builtin_bit_cast(float, hu.x & 0xffff0000u);
  hx[2] = __builtin_bit_cast(float, hu.y << 16);
  hx[3] = __builtin_bit_cast(float, hu.y & 0xffff0000u);
  float wv[8];
  load8(lw3 + (size_t)k0 * 2, wv);
  float p0 = 0.f, p1 = 0.f;
#pragma unroll
  for (int i = 0; i < 4; i++) {
    p0 = fmaf(hx[i], wv[2 * i], p0);
    p1 = fmaf(hx[i], wv[2 * i + 1], p1);
  }
#pragma unroll
  for (int off = 32; off >= 1; off >>= 1) {
    p0 += __shfl_xor(p0, off);
    p1 += __shfl_xor(p1, off);
  }
  if (lane == 0) {
    float l0 = p0 + b2f(lb3[0]);
    float l1 = p1 + b2f(lb3[1]);
    float mx = fmaxf(l0, l1);
    float q0 = __expf(l0 - mx), q1 = __expf(l1 - mx);
    float si = 1.f / (q0 + q1);
    out[row * 2 + 0] = l0;
    out[row * 2 + 1] = l1;
    out[2 * n + row * 2 + 0] = q0 * si;
    out[2 * n + row * 2 + 1] = q1 * si;
  }
}

extern "C" void kernel_launch(void* const* d_in, const int* in_sizes, int n_in,
                              void* d_out, int out_size, void* d_ws, size_t ws_size,
                              hipStream_t stream) {
  (void)in_sizes; (void)n_in; (void)out_size; (void)ws_size;
  const void* x_raw = d_in[0];
  const void* ei_raw = d_in[1];
  const void *wl[4], *bl[4], *wr[4], *br[4], *att[4], *bg[4];
  for (int i = 0; i < 4; i++) {
    wl[i] = d_in[2 + i * 6 + 0];
    bl[i] = d_in[2 + i * 6 + 1];
    wr[i] = d_in[2 + i * 6 + 2];
    br[i] = d_in[2 + i * 6 + 3];
    att[i] = d_in[2 + i * 6 + 4];
    bg[i] = d_in[2 + i * 6 + 5];
  }
  const void* lw1 = d_in[26];
  const void* lb1 = d_in[27];
  const void* lw2 = d_in[28];
  const void* lb2 = d_in[29];
  const void* lw3 = d_in[30];
  const void* lb3 = d_in[31];

  size_t off = 0;
  auto alloc = [&](size_t bytes) -> void* {
    off = (off + 255) & ~(size_t)255;
    void* p = (char*)d_ws + off;
    off += bytes;
    return p;
  };
  int* esrc = (int*)alloc(NE * 4);
  int* edst = (int*)alloc(NE * 4);
  int* counts = (int*)alloc(NN * 4);
  int* rowptr = (int*)alloc((NN + 1) * 4);
  int* cursor = (int*)alloc(NN * 4);
  int* col = (int*)alloc((NE + NN) * 4);
  u16* cb = (u16*)alloc(4 * 1024 * 2);
  u16* attv = (u16*)alloc(4 * 512 * 2);
  u16* bgv = (u16*)alloc(4 * 512 * 2);
  u16* lb1v = (u16*)alloc(512 * 2);
  u16* lb2v = (u16*)alloc(256 * 2);
  u16* lw3v = (u16*)alloc(512 * 2);
  u16* lb3v = (u16*)alloc(2 * 2);
  u16* comb0 = (u16*)alloc((size_t)1024 * 1024 * 2);
  u16* combL[4];
  combL[0] = comb0;
  for (int l = 1; l < 4; l++) combL[l] = (u16*)alloc((size_t)1024 * 512 * 2);
  u16* lw1T = (u16*)alloc((size_t)512 * 512 * 2);
  u16* lw2T = (u16*)alloc((size_t)256 * 512 * 2);
  u16* xc = (u16*)alloc((size_t)NN * DIN_ * 2);
  u16* X0 = (u16*)alloc((size_t)NN * 1024 * 2);
  u16* X1 = (u16*)alloc((size_t)NN * 1024 * 2);
  u16* mlp1 = xc;                       // xc dead after layer-1 GEMM
  u16* mlp2 = xc + (size_t)NN * 512;

  // --- CSR stage 1 ---
  hipMemsetAsync(counts, 0, NN * 4, stream);
  int ET = NE + NN;
  k_edges<<<(ET + 255) / 256, 256, 0, stream>>>(ei_raw, esrc, edst, counts);
  k_scan<<<1, 512, 0, stream>>>(counts, rowptr, cursor, NN);

  // --- fused scatter + prep ---
  Prep pa;
  pa.esrc = esrc;
  pa.edst = edst;
  pa.cursor = cursor;
  pa.col = col;
  pa.xin = x_raw;
  pa.xout = xc;
  for (int l = 0; l < 4; l++) {
    pa.vin[l * 4 + 0] = bl[l];  pa.vout[l * 4 + 0] = cb + l * 1024;        pa.vn[l * 4 + 0] = 512;
    pa.vin[l * 4 + 1] = br[l];  pa.vout[l * 4 + 1] = cb + l * 1024 + 512;  pa.vn[l * 4 + 1] = 512;
    pa.vin[l * 4 + 2] = att[l]; pa.vout[l * 4 + 2] = attv + l * 512;       pa.vn[l * 4 + 2] = 512;
    pa.vin[l * 4 + 3] = bg[l];  pa.vout[l * 4 + 3] = bgv + l * 512;        pa.vn[l * 4 + 3] = 512;
  }
  pa.vin[16] = lb1; pa.vout[16] = lb1v; pa.vn[16] = 512;
  pa.vin[17] = lb2; pa.vout[17] = lb2v; pa.vn[17] = 256;
  pa.vin[18] = lw3; pa.vout[18] = lw3v; pa.vn[18] = 512;
  pa.vin[19] = lb3; pa.vout[19] = lb3v; pa.vn[19] = 2;
  const void* tin[10] = {wl[0], wr[0], wl[1], wr[1], wl[2], wr[2], wl[3], wr[3], lw1, lw2};
  u16* tout[10] = {comb0, comb0 + (size_t)512 * 1024,
                   combL[1], combL[1] + (size_t)512 * 512,
                   combL[2], combL[2] + (size_t)512 * 512,
                   combL[3], combL[3] + (size_t)512 * 512,
                   lw1T, lw2T};
  int tK[10] = {1024, 1024, 512, 512, 512, 512, 512, 512, 512, 512};
  int tN[10] = {512, 512, 512, 512, 512, 512, 512, 512, 512, 256};
  int acc_off = 0;
  for (int i = 0; i < 10; i++) {
    pa.tin[i] = tin[i];
    pa.tout[i] = tout[i];
    pa.tK[i] = tK[i];
    pa.tN[i] = tN[i];
    pa.toff[i] = acc_off;
    acc_off += (tN[i] >> 5) * (tK[i] >> 5);
  }
  k_prep<<<SBLK + XBLK + 20 + acc_off, 256, 0, stream>>>(pa);

  auto gemm = [&](const u16* A, int lda, const u16* Bt, const u16* bias, u16* C,
                  int M, int Nn, int K, int act) {
    int tiles_m = (M + 127) >> 7;
    int tiles_n = Nn >> 7;
    int ln = (tiles_n == 8) ? 3 : (tiles_n == 4) ? 2 : 1;
    int mgrp = (tiles_m + 7) >> 3;
    int blocks = (mgrp << 3) * tiles_n;
    k_gemm128<<<blocks, 256, 0, stream>>>(A, lda, Bt, bias, C, M, Nn, K, act, tiles_m, ln);
  };
  auto attn = [&](u16* xlr, int l) {
    k_attn5<<<(NN * 64 + 255) / 256, 256, 0, stream>>>(xlr, attv + l * 512, bgv + l * 512,
                                                       rowptr, col, NN);
  };

  // Layer 1
  gemm(xc, 1024, comb0, cb + 0 * 1024, X0, NN, 1024, 1024, 0);
  attn(X0, 0);
  // Layer 2
  gemm(X0 + 512, 1024, combL[1], cb + 1 * 1024, X1, NN, 1024, 512, 0);
  attn(X1, 1);
  // Layer 3
  gemm(X1 + 512, 1024, combL[2], cb + 2 * 1024, X0, NN, 1024, 512, 0);
  attn(X0, 2);
  // Layer 4
  gemm(X0 + 512, 1024, combL[3], cb + 3 * 1024, X1, NN, 1024, 512, 0);
  attn(X1, 3);

  // MLP head
  gemm(X1 + 512, 1024, lw1T, lb1v, mlp1, NN, 512, 512, 1);
  gemm(mlp1, 512, lw2T, lb2v, mlp2, NN, 256, 512, 1);
  k_head<<<(NN * 64 + 255) / 256, 256, 0, stream>>>(mlp2, lw3v, lb3v, (float*)d_out, NN);
}

// Round 13
// 379.982 us; speedup vs baseline: 1.0646x; 1.0646x over previous
//
#include <hip/hip_runtime.h>
#include <cstdint>

#define NN 10000
#define NE 80000
#define DIN_ 1024
#define HH 512

typedef __attribute__((ext_vector_type(8))) short bf16x8;
typedef __attribute__((ext_vector_type(4))) float f32x4;
typedef unsigned short u16;
typedef unsigned int u32;

static __device__ __forceinline__ float b2f(u16 u) {
  u32 i = ((u32)u) << 16;
  return __builtin_bit_cast(float, i);
}
static __device__ __forceinline__ u16 f2b(float f) {
  u32 i = __builtin_bit_cast(u32, f);
  u32 r = (i + 0x7fffu + ((i >> 16) & 1u)) >> 16;
  return (u16)r;
}
static __device__ __forceinline__ void unpack8(uint4 u, float* f) {
  f[0] = __builtin_bit_cast(float, u.x << 16);
  f[1] = __builtin_bit_cast(float, u.x & 0xffff0000u);
  f[2] = __builtin_bit_cast(float, u.y << 16);
  f[3] = __builtin_bit_cast(float, u.y & 0xffff0000u);
  f[4] = __builtin_bit_cast(float, u.z << 16);
  f[5] = __builtin_bit_cast(float, u.z & 0xffff0000u);
  f[6] = __builtin_bit_cast(float, u.w << 16);
  f[7] = __builtin_bit_cast(float, u.w & 0xffff0000u);
}
static __device__ __forceinline__ void load8(const u16* p, float* f) { unpack8(*(const uint4*)p, f); }

#define ASYNC_CP16(gp, lp)                                                        \
  __builtin_amdgcn_global_load_lds((__attribute__((address_space(1))) void*)(gp), \
                                   (__attribute__((address_space(3))) void*)(lp), \
                                   16, 0, 0)

// per-block dtype flags
static __device__ __forceinline__ int float_flag(const u16* xw) {
  __shared__ int c;
  if (threadIdx.x == 0) c = 0;
  __syncthreads();
  int bad = 0;
  for (int i = threadIdx.x; i < 2048; i += blockDim.x) {
    u32 e = (xw[i] >> 7) & 0xFFu;
    if (e >= 140u) bad++;  // |v|>=2^13 impossible for bf16 x~N(0,1)
  }
  if (bad) atomicAdd(&c, bad);
  __syncthreads();
  return c > 64;
}
static __device__ __forceinline__ int int64_flag(const u32* ew) {
  __shared__ int c;
  if (threadIdx.x == 0) c = 0;
  __syncthreads();
  int z = 0;
  for (int i = threadIdx.x; i < 256; i += blockDim.x)
    if (ew[2 * i + 1] == 0u) z++;
  if (z) atomicAdd(&c, z);
  __syncthreads();
  return c > 200;
}

// ---------------- edges: dtype cvt + degree count ----------------
__global__ void k_edges(const void* ei, int* esrc, int* edst, int* counts) {
  int f64 = int64_flag((const u32*)ei);
  int i = blockIdx.x * 256 + threadIdx.x;
  if (i < NE) {
    int sv, dv;
    if (f64) {
      sv = (int)((const long long*)ei)[i];
      dv = (int)((const long long*)ei)[NE + i];
    } else {
      sv = ((const int*)ei)[i];
      dv = ((const int*)ei)[NE + i];
    }
    esrc[i] = sv;
    edst[i] = dv;
    atomicAdd(&counts[dv], 1);
  } else if (i < NE + NN) {
    atomicAdd(&counts[i - NE], 1);  // self-loop
  }
}

// ---------------- work-efficient single-block scan (512 x 20) ----------------
__global__ __launch_bounds__(512) void k_scan(const int* counts, int* rowptr, int* cursor, int n) {
  __shared__ int lds[512];
  const int PER = 20;
  int t = threadIdx.x;
  int base = t * PER;
  int v[PER];
  int sum = 0;
#pragma unroll
  for (int i = 0; i < PER; i++) {
    int idx = base + i;
    v[i] = (idx < n) ? counts[idx] : 0;
    sum += v[i];
  }
  lds[t] = sum;
  __syncthreads();
  for (int off = 1; off < 512; off <<= 1) {
    int x = (t >= off) ? lds[t - off] : 0;
    __syncthreads();
    lds[t] += x;
    __syncthreads();
  }
  int run = (t > 0) ? lds[t - 1] : 0;
#pragma unroll
  for (int i = 0; i < PER; i++) {
    int idx = base + i;
    if (idx < n) {
      cursor[idx] = run;
      run += v[i];
      rowptr[idx + 1] = run;
    }
  }
  if (t == 0) rowptr[0] = 0;
}

// ---------------- fused: scatter + x convert + 20 vectors + 10 weight transposes ----------------
#define SBLK 352   // scatter blocks: ceil((NE+NN)/256)
#define XBLK 2048
struct Prep {
  const int* esrc;
  const int* edst;
  int* cursor;
  int* col;
  const void* xin;
  u16* xout;
  const void* vin[20];
  u16* vout[20];
  int vn[20];
  const void* tin[10];
  u16* tout[10];
  int tK[10], tN[10], toff[10];
};
__global__ void k_prep(Prep a) {
  __shared__ u16 tt[32][33];
  int b = blockIdx.x;
  if (b < SBLK) {
    int i = b * 256 + threadIdx.x;
    if (i < NE) {
      int p = atomicAdd(&a.cursor[a.edst[i]], 1);
      a.col[p] = a.esrc[i];
    } else if (i < NE + NN) {
      int v = i - NE;
      int p = atomicAdd(&a.cursor[v], 1);
      a.col[p] = v;  // self-loop
    }
    return;
  }
  b -= SBLK;
  int f = float_flag((const u16*)a.xin);
  if (b < XBLK) {
    const int total = NN * DIN_ / 8;
    for (int g = b * 256 + threadIdx.x; g < total; g += XBLK * 256) {
      u16 o[8];
      if (f) {
        const float* p = (const float*)a.xin + (size_t)g * 8;
#pragma unroll
        for (int i = 0; i < 8; i++) o[i] = f2b(p[i]);
      } else {
        *(uint4*)o = *((const uint4*)a.xin + g);
      }
      *((uint4*)a.xout + g) = *(const uint4*)o;
    }
  } else if (b < XBLK + 20) {
    int v = b - XBLK;
    const void* in = a.vin[v];
    u16* out = a.vout[v];
    int n = a.vn[v];
    for (int i = threadIdx.x; i < n; i += 256)
      out[i] = f ? f2b(((const float*)in)[i]) : ((const u16*)in)[i];
  } else {
    int tb = b - XBLK - 20;
    int seg = 0;
#pragma unroll
    for (int i = 1; i < 10; i++)
      if (tb >= a.toff[i]) seg = i;
    int tl = tb - a.toff[seg];
    int K = a.tK[seg], N = a.tN[seg];
    int tiles_n = N >> 5;
    int n0 = (tl % tiles_n) << 5, k0 = (tl / tiles_n) << 5;
    const void* in = a.tin[seg];
    u16* out = a.tout[seg];
    int tx = threadIdx.x & 31, ty = threadIdx.x >> 5;
    for (int r = ty; r < 32; r += 8) {
      size_t idx = (size_t)(k0 + r) * N + n0 + tx;
      tt[r][tx] = f ? f2b(((const float*)in)[idx]) : ((const u16*)in)[idx];
    }
    __syncthreads();
    for (int r = ty; r < 32; r += 8) out[(size_t)(n0 + r) * K + k0 + tx] = tt[tx][r];
  }
}

// ---------------- 128x128 MFMA GEMM, BK=64, XOR-swizzled LDS, XCD-aware mapping ----------------
__global__ __launch_bounds__(256) void k_gemm128(const u16* __restrict__ A, int lda,
                                                 const u16* __restrict__ Bt,
                                                 const u16* __restrict__ bias,
                                                 u16* __restrict__ C,
                                                 int M, int N, int K, int act,
                                                 int tiles_m, int ln_tiles_n) {
  __shared__ u16 sA[2 * 128 * 32];
  __shared__ u16 sB[2 * 128 * 32];
  int id = blockIdx.x;
  int xcd = id & 7;
  int rest = id >> 3;
  int xt = rest & ((1 << ln_tiles_n) - 1);
  int yt = ((rest >> ln_tiles_n) << 3) + xcd;
  if (yt >= tiles_m) return;
  int m0 = yt << 7, n0 = xt << 7;
  int t = threadIdx.x;
  int wave = t >> 6, lane = t & 63;

  int srow = t >> 2;
  int sk = ((t & 3) ^ ((t >> 3) & 3)) * 8;  // XOR-swizzled k-chunk
  const u16* agp[4];
  const u16* bgp[4];
  u16* la[4];
  u16* lb[4];
#pragma unroll
  for (int q = 0; q < 4; q++) {
    int h = q >> 1;
    int row = ((q & 1) << 6) + srow;
    int ra = m0 + row;
    ra = ra < M ? ra : M - 1;
    agp[q] = A + (size_t)ra * lda + h * 32 + sk;
    bgp[q] = Bt + (size_t)(n0 + row) * K + h * 32 + sk;
    int lofs = h * 4096 + (((q & 1) << 8) + t) * 8;
    la[q] = sA + lofs;
    lb[q] = sB + lofs;
  }

  int wm = (wave >> 1) << 6, wn = (wave & 1) << 6;
  int lr = lane & 15;
  int kcs = (((lane >> 4) ^ ((lr >> 1) & 3))) * 8;

  f32x4 acc[4][4];
#pragma unroll
  for (int i = 0; i < 4; i++)
#pragma unroll
    for (int j = 0; j < 4; j++) acc[i][j] = (f32x4){0.f, 0.f, 0.f, 0.f};

  for (int k0 = 0; k0 < K; k0 += 64) {
#pragma unroll
    for (int q = 0; q < 4; q++) ASYNC_CP16(agp[q] + k0, la[q]);
#pragma unroll
    for (int q = 0; q < 4; q++) ASYNC_CP16(bgp[q] + k0, lb[q]);
    __syncthreads();
    bf16x8 a[2][4], b[2][4];
#pragma unroll
    for (int s = 0; s < 2; s++) {
#pragma unroll
      for (int i = 0; i < 4; i++) a[s][i] = *(const bf16x8*)(sA + s * 4096 + (wm + i * 16 + lr) * 32 + kcs);
#pragma unroll
      for (int j = 0; j < 4; j++) b[s][j] = *(const bf16x8*)(sB + s * 4096 + (wn + j * 16 + lr) * 32 + kcs);
    }
#pragma unroll
    for (int s = 0; s < 2; s++)
#pragma unroll
      for (int i = 0; i < 4; i++)
#pragma unroll
        for (int j = 0; j < 4; j++)
          acc[i][j] = __builtin_amdgcn_mfma_f32_16x16x32_bf16(a[s][i], b[s][j], acc[i][j], 0, 0, 0);
    __syncthreads();
  }

  int rbase = (lane >> 4) << 2;
#pragma unroll
  for (int j = 0; j < 4; j++) {
    int colc = n0 + wn + j * 16 + lr;
    float bv = b2f(bias[colc]);
#pragma unroll
    for (int i = 0; i < 4; i++) {
#pragma unroll
      for (int r = 0; r < 4; r++) {
        int row = m0 + wm + i * 16 + rbase + r;
        if (row < M) {
          float v = acc[i][j][r] + bv;
          if (act) v = fmaxf(v, 0.f);
          C[(size_t)row * N + colc] = f2b(v);
        }
      }
    }
  }
}

// ---------------- single-pass GATv2 attention, 2-edge ILP, 1 exp per edge ----------------
__global__ __launch_bounds__(256) void k_attn5(u16* __restrict__ xlr,
                                               const u16* __restrict__ att, const u16* __restrict__ bias,
                                               const int* __restrict__ rowptr, const int* __restrict__ col,
                                               int n) {
  int node = (blockIdx.x * 256 + threadIdx.x) >> 6;
  if (node >= n) return;
  int lane = threadIdx.x & 63;
  int h0 = lane * 8;
  float a[8], r[8];
  load8(att + h0, a);
  load8(xlr + (size_t)node * 1024 + 512 + h0, r);
  int e0 = rowptr[node], e1 = rowptr[node + 1];

  float m = -3e38f, s = 0.f;
  float acc[8] = {0.f, 0.f, 0.f, 0.f, 0.f, 0.f, 0.f, 0.f};
  int j0 = col[e0];
  int j1 = col[(e0 + 1 < e1) ? e0 + 1 : e0];
  uint4 raw0 = *(const uint4*)(xlr + (size_t)j0 * 1024 + h0);
  uint4 raw1 = *(const uint4*)(xlr + (size_t)j1 * 1024 + h0);

  for (int e = e0; e < e1; e += 2) {
    bool has2 = (e + 1 < e1);
    int jn0 = col[(e + 2 < e1) ? e + 2 : e1 - 1];
    int jn1 = col[(e + 3 < e1) ? e + 3 : e1 - 1];
    uint4 p0 = *(const uint4*)(xlr + (size_t)jn0 * 1024 + h0);  // prefetch next pair
    uint4 p1 = *(const uint4*)(xlr + (size_t)jn1 * 1024 + h0);
    float x0[8], x1[8];
    unpack8(raw0, x0);
    unpack8(raw1, x1);
    float pa = 0.f, pb = 0.f;
#pragma unroll
    for (int i = 0; i < 8; i++) {
      float z0 = x0[i] + r[i];
      z0 = z0 > 0.f ? z0 : 0.2f * z0;
      pa = fmaf(a[i], z0, pa);
      float z1 = x1[i] + r[i];
      z1 = z1 > 0.f ? z1 : 0.2f * z1;
      pb = fmaf(a[i], z1, pb);
    }
#pragma unroll
    for (int off = 32; off >= 1; off >>= 1) {
      pa += __shfl_xor(pa, off);
      pb += __shfl_xor(pb, off);
    }
    // edge A: exactly one exp on the critical path (new-max edge has weight 1)
    if (pa > m) {
      float al = __expf(m - pa);  // first edge: exp(-inf)=0
      s = fmaf(s, al, 1.f);
#pragma unroll
      for (int i = 0; i < 8; i++) acc[i] = fmaf(acc[i], al, x0[i]);
      m = pa;
    } else {
      float w = __expf(pa - m);
      s += w;
#pragma unroll
      for (int i = 0; i < 8; i++) acc[i] = fmaf(w, x0[i], acc[i]);
    }
    if (has2) {
      if (pb > m) {
        float al = __expf(m - pb);
        s = fmaf(s, al, 1.f);
#pragma unroll
        for (int i = 0; i < 8; i++) acc[i] = fmaf(acc[i], al, x1[i]);
        m = pb;
      } else {
        float w = __expf(pb - m);
        s += w;
#pragma unroll
        for (int i = 0; i < 8; i++) acc[i] = fmaf(w, x1[i], acc[i]);
      }
    }
    raw0 = p0;
    raw1 = p1;
  }
  float inv = 1.f / (s + 1e-16f);

  float bv[8];
  load8(bias + h0, bv);
  uint4 o;
  u32 p8[8];
#pragma unroll
  for (int i = 0; i < 8; i++) {
    float v = fmaf(acc[i], inv, bv[i]);
    v = fmaxf(v, 0.f);
    p8[i] = f2b(v);
  }
  o.x = p8[0] | (p8[1] << 16);
  o.y = p8[2] | (p8[3] << 16);
  o.z = p8[4] | (p8[5] << 16);
  o.w = p8[6] | (p8[7] << 16);
  *(uint4*)(xlr + (size_t)node * 1024 + 512 + h0) = o;  // in-place over xr half
}

// ---------------- final linear (256->2) + softmax; fp32 out ----------------
__global__ __launch_bounds__(256) void k_head(const u16* __restrict__ h2, const u16* __restrict__ lw3,
                                              const u16* __restrict__ lb3, float* __restrict__ out, int n) {
  int row = (blockIdx.x * 256 + threadIdx.x) >> 6;
  if (row >= n) return;
  int lane = threadIdx.x & 63;
  int k0 = lane * 4;
  uint2 hu = *(const uint2*)(h2 + (size_t)row * 256 + k0);
  float hx[4];
  hx[0] = __builtin_bit_cast(float, hu.x << 16);
  hx[1] = __builtin_bit_cast(float, hu.x & 0xffff0000u);
  hx[2] = __builtin_bit_cast(float, hu.y << 16);
  hx[3] = __builtin_bit_cast(float, hu.y & 0xffff0000u);
  float wv[8];
  load8(lw3 + (size_t)k0 * 2, wv);
  float p0 = 0.f, p1 = 0.f;
#pragma unroll
  for (int i = 0; i < 4; i++) {
    p0 = fmaf(hx[i], wv[2 * i], p0);
    p1 = fmaf(hx[i], wv[2 * i + 1], p1);
  }
#pragma unroll
  for (int off = 32; off >= 1; off >>= 1) {
    p0 += __shfl_xor(p0, off);
    p1 += __shfl_xor(p1, off);
  }
  if (lane == 0) {
    float l0 = p0 + b2f(lb3[0]);
    float l1 = p1 + b2f(lb3[1]);
    float mx = fmaxf(l0, l1);
    float q0 = __expf(l0 - mx), q1 = __expf(l1 - mx);
    float si = 1.f / (q0 + q1);
    out[row * 2 + 0] = l0;
    out[row * 2 + 1] = l1;
    out[2 * n + row * 2 + 0] = q0 * si;
    out[2 * n + row * 2 + 1] = q1 * si;
  }
}

extern "C" void kernel_launch(void* const* d_in, const int* in_sizes, int n_in,
                              void* d_out, int out_size, void* d_ws, size_t ws_size,
                              hipStream_t stream) {
  (void)in_sizes; (void)n_in; (void)out_size; (void)ws_size;
  const void* x_raw = d_in[0];
  const void* ei_raw = d_in[1];
  const void *wl[4], *bl[4], *wr[4], *br[4], *att[4], *bg[4];
  for (int i = 0; i < 4; i++) {
    wl[i] = d_in[2 + i * 6 + 0];
    bl[i] = d_in[2 + i * 6 + 1];
    wr[i] = d_in[2 + i * 6 + 2];
    br[i] = d_in[2 + i * 6 + 3];
    att[i] = d_in[2 + i * 6 + 4];
    bg[i] = d_in[2 + i * 6 + 5];
  }
  const void* lw1 = d_in[26];
  const void* lb1 = d_in[27];
  const void* lw2 = d_in[28];
  const void* lb2 = d_in[29];
  const void* lw3 = d_in[30];
  const void* lb3 = d_in[31];

  size_t off = 0;
  auto alloc = [&](size_t bytes) -> void* {
    off = (off + 255) & ~(size_t)255;
    void* p = (char*)d_ws + off;
    off += bytes;
    return p;
  };
  int* esrc = (int*)alloc(NE * 4);
  int* edst = (int*)alloc(NE * 4);
  int* counts = (int*)alloc(NN * 4);
  int* rowptr = (int*)alloc((NN + 1) * 4);
  int* cursor = (int*)alloc(NN * 4);
  int* col = (int*)alloc((NE + NN) * 4);
  u16* cb = (u16*)alloc(4 * 1024 * 2);
  u16* attv = (u16*)alloc(4 * 512 * 2);
  u16* bgv = (u16*)alloc(4 * 512 * 2);
  u16* lb1v = (u16*)alloc(512 * 2);
  u16* lb2v = (u16*)alloc(256 * 2);
  u16* lw3v = (u16*)alloc(512 * 2);
  u16* lb3v = (u16*)alloc(2 * 2);
  u16* comb0 = (u16*)alloc((size_t)1024 * 1024 * 2);
  u16* combL[4];
  combL[0] = comb0;
  for (int l = 1; l < 4; l++) combL[l] = (u16*)alloc((size_t)1024 * 512 * 2);
  u16* lw1T = (u16*)alloc((size_t)512 * 512 * 2);
  u16* lw2T = (u16*)alloc((size_t)256 * 512 * 2);
  u16* xc = (u16*)alloc((size_t)NN * DIN_ * 2);
  u16* X0 = (u16*)alloc((size_t)NN * 1024 * 2);
  u16* X1 = (u16*)alloc((size_t)NN * 1024 * 2);
  u16* mlp1 = xc;                       // xc dead after layer-1 GEMM
  u16* mlp2 = xc + (size_t)NN * 512;

  // --- CSR stage 1 ---
  hipMemsetAsync(counts, 0, NN * 4, stream);
  int ET = NE + NN;
  k_edges<<<(ET + 255) / 256, 256, 0, stream>>>(ei_raw, esrc, edst, counts);
  k_scan<<<1, 512, 0, stream>>>(counts, rowptr, cursor, NN);

  // --- fused scatter + prep ---
  Prep pa;
  pa.esrc = esrc;
  pa.edst = edst;
  pa.cursor = cursor;
  pa.col = col;
  pa.xin = x_raw;
  pa.xout = xc;
  for (int l = 0; l < 4; l++) {
    pa.vin[l * 4 + 0] = bl[l];  pa.vout[l * 4 + 0] = cb + l * 1024;        pa.vn[l * 4 + 0] = 512;
    pa.vin[l * 4 + 1] = br[l];  pa.vout[l * 4 + 1] = cb + l * 1024 + 512;  pa.vn[l * 4 + 1] = 512;
    pa.vin[l * 4 + 2] = att[l]; pa.vout[l * 4 + 2] = attv + l * 512;       pa.vn[l * 4 + 2] = 512;
    pa.vin[l * 4 + 3] = bg[l];  pa.vout[l * 4 + 3] = bgv + l * 512;        pa.vn[l * 4 + 3] = 512;
  }
  pa.vin[16] = lb1; pa.vout[16] = lb1v; pa.vn[16] = 512;
  pa.vin[17] = lb2; pa.vout[17] = lb2v; pa.vn[17] = 256;
  pa.vin[18] = lw3; pa.vout[18] = lw3v; pa.vn[18] = 512;
  pa.vin[19] = lb3; pa.vout[19] = lb3v; pa.vn[19] = 2;
  const void* tin[10] = {wl[0], wr[0], wl[1], wr[1], wl[2], wr[2], wl[3], wr[3], lw1, lw2};
  u16* tout[10] = {comb0, comb0 + (size_t)512 * 1024,
                   combL[1], combL[1] + (size_t)512 * 512,
                   combL[2], combL[2] + (size_t)512 * 512,
                   combL[3], combL[3] + (size_t)512 * 512,
                   lw1T, lw2T};
  int tK[10] = {1024, 1024, 512, 512, 512, 512, 512, 512, 512, 512};
  int tN[10] = {512, 512, 512, 512, 512, 512, 512, 512, 512, 256};
  int acc_off = 0;
  for (int i = 0; i < 10; i++) {
    pa.tin[i] = tin[i];
    pa.tout[i] = tout[i];
    pa.tK[i] = tK[i];
    pa.tN[i] = tN[i];
    pa.toff[i] = acc_off;
    acc_off += (tN[i] >> 5) * (tK[i] >> 5);
  }
  k_prep<<<SBLK + XBLK + 20 + acc_off, 256, 0, stream>>>(pa);

  auto gemm = [&](const u16* A, int lda, const u16* Bt, const u16* bias, u16* C,
                  int M, int Nn, int K, int act) {
    int tiles_m = (M + 127) >> 7;
    int tiles_n = Nn >> 7;
    int ln = (tiles_n == 8) ? 3 : (tiles_n == 4) ? 2 : 1;
    int mgrp = (tiles_m + 7) >> 3;
    int blocks = (mgrp << 3) * tiles_n;
    k_gemm128<<<blocks, 256, 0, stream>>>(A, lda, Bt, bias, C, M, Nn, K, act, tiles_m, ln);
  };
  auto attn = [&](u16* xlr, int l) {
    k_attn5<<<(NN * 64 + 255) / 256, 256, 0, stream>>>(xlr, attv + l * 512, bgv + l * 512,
                                                       rowptr, col, NN);
  };

  // Layer 1
  gemm(xc, 1024, comb0, cb + 0 * 1024, X0, NN, 1024, 1024, 0);
  attn(X0, 0);
  // Layer 2
  gemm(X0 + 512, 1024, combL[1], cb + 1 * 1024, X1, NN, 1024, 512, 0);
  attn(X1, 1);
  // Layer 3
  gemm(X1 + 512, 1024, combL[2], cb + 2 * 1024, X0, NN, 1024, 512, 0);
  attn(X0, 2);
  // Layer 4
  gemm(X0 + 512, 1024, combL[3], cb + 3 * 1024, X1, NN, 1024, 512, 0);
  attn(X1, 3);

  // MLP head
  gemm(X1 + 512, 1024, lw1T, lb1v, mlp1, NN, 512, 512, 1);
  gemm(mlp1, 512, lw2T, lb2v, mlp2, NN, 256, 512, 1);
  k_head<<<(NN * 64 + 255) / 256, 256, 0, stream>>>(mlp2, lw3v, lb3v, (float*)d_out, NN);
}